// Round 19
// baseline (230.097 us; speedup 1.0000x reference)
//
#include <hip/hip_runtime.h>

#define B_DIM 4
#define T_DIM 300
#define U_DIM 80
#define UP1   81
#define V_DIM 1024
#define NINNER 512
#define NROWS (B_DIM * T_DIM * UP1)   /* 97200 */
#define EP_ROWS (B_DIM * T_DIM)       /* 1200 */
#define DP_ROWS (B_DIM * UP1)         /* 324 */
#define NDIAG 380                      /* t+u diagonals */
#define ZSTR  168                      /* Z row stride in floats: 4 pad + 162, 16B-aligned */
#define ZROWS (B_DIM * NDIAG + 8)      /* + 8 NEG slack rows (no-clamp ALOAD) */
#define WF_PART 163840                 /* 512 cols x 320 k, per half of Wf */
#define NRG   6080                     /* 16-row groups in hpk (>= 97216/16, padded) */
#define LOG2E 1.44269504088896341f
#define LN2   0.69314718055994531f
#define NEGF  -1e30f

typedef float f32x4 __attribute__((ext_vector_type(4)));
typedef short short8 __attribute__((ext_vector_type(8)));
typedef short short4v __attribute__((ext_vector_type(4)));
typedef __bf16 bf16x8 __attribute__((ext_vector_type(8)));
typedef int int2v __attribute__((ext_vector_type(2)));

static __device__ __forceinline__ short f2bf(float f) {
  return (short)__builtin_bit_cast(unsigned short, (__bf16)f);  // native cvt (RNE)
}
static __device__ __forceinline__ float bf2f(short s) {
  unsigned int u = ((unsigned int)(unsigned short)s) << 16;
  return __builtin_bit_cast(float, u);
}
static __device__ __forceinline__ float tanh_fast(float x) {
  float e = __builtin_amdgcn_exp2f(x * 2.88539008177792681f); // exp(2x)
  return 1.0f - 2.0f * __builtin_amdgcn_rcpf(e + 1.0f);
}
// base-2 logsumexp of 2 terms (finite-NEG safe)
static __device__ __forceinline__ float lse2_2(float a, float b) {
  float mx = fmaxf(a, b), mn = fminf(a, b);
  return mx + __builtin_amdgcn_logf(1.0f + __builtin_amdgcn_exp2f(mn - mx));
}
// DPP wave_ror:1 — dst[i] = src[(i+63)&63]; VALU pipe, no LDS unit (r11).
static __device__ __forceinline__ float ror1f(float x) {
  int r = __builtin_amdgcn_update_dpp(0, __builtin_bit_cast(int, x),
                                      0x13C /*WAVE_ROR1*/, 0xF, 0xF, true);
  return __builtin_bit_cast(float, r);
}
static __device__ __forceinline__ float readlanef(float x, int l) {
  return __builtin_bit_cast(float,
      __builtin_amdgcn_readlane(__builtin_bit_cast(int, x), l));
}
// 16B load at 4B alignment (Z operand quads sit at odd float indices)
static __device__ __forceinline__ f32x4 load4u(const float* p) {
  f32x4 v;
  __builtin_memcpy(&v, p, 16);
  return v;
}
static __device__ __forceinline__ long load8(const void* p) {
  long v;
  __builtin_memcpy(&v, p, 8);
  return v;
}
// HW fp8 e4m3 pack: 2 f32 -> 2 fp8 bytes; HI must be an immediate (r17 fix).
template <bool HI>
static __device__ __forceinline__ int pkf8(float a, float b, int old) {
  return __builtin_amdgcn_cvt_pk_fp8_f32(a, b, old, HI);
}

// ---------------- Kernel 0: weight cvt/pack + Z NEG-prefill -----------------
#define CVT_NF 81920
#define CVT_NP 131072
#define FILL_N4 ((ZROWS * ZSTR) / 4)   /* 64176 */
__global__ __launch_bounds__(256) void cvt_kernel(
    const float* __restrict__ Wf, const float* __restrict__ Wp,
    short* __restrict__ WfB, char* __restrict__ WpB8, float* __restrict__ Z) {
  int idx = blockIdx.x * 256 + threadIdx.x;
  if (idx < CVT_NF) {
    float4 v = ((const float4*)Wf)[idx];
    int flat = idx * 4;
    int c = flat / 640;
    int kc = flat - c * 640;
    int part = (kc >= 320);
    int k0 = kc - (part ? 320 : 0);
    int dest = (part ? WF_PART : 0)
             + ((c >> 4) * 10 + (k0 >> 5)) * 512
             + (((k0 >> 3) & 3) * 16 + (c & 15)) * 8 + (k0 & 7);
    short4v o;
    o[0] = f2bf(v.x); o[1] = f2bf(v.y); o[2] = f2bf(v.z); o[3] = f2bf(v.w);
    *(short4v*)(WfB + dest) = o;
  } else if (idx < CVT_NF + CVT_NP) {
    int j = idx - CVT_NF;
    float4 v = ((const float4*)Wp)[j];
    int flat = j * 4;
    int c = flat >> 9;
    int k0 = flat & 511;
    int dest = ((c >> 4) * 16 + (k0 >> 5)) * 512
             + (((k0 >> 3) & 3) * 16 + (c & 15)) * 8 + (k0 & 7);
    int w = pkf8<false>(v.x, v.y, 0);
    w = pkf8<true>(v.z, v.w, w);
    *(int*)(WpB8 + dest) = w;     // dest is 4-aligned (k0&7 in {0,4})
  } else {
    int i = idx - (CVT_NF + CVT_NP);
    if (i < FILL_N4) ((f32x4*)Z)[i] = (f32x4){NEGF, NEGF, NEGF, NEGF};
  }
}

// ---------------- Kernel 1: enc/dec projections (MFMA bf16) ----------------
// NOTE: no min-waves arg — min-waves>=4 on MFMA kernels splits the unified
// RF (Arch 64 / AGPR 64) and spills (r2/r3).
#define EP_BLOCKS 19
__global__ __launch_bounds__(256) void proj_kernel(
    const float* __restrict__ enc, const float* __restrict__ dec,
    const short* __restrict__ WfB, const float* __restrict__ bfv,
    short* __restrict__ epB, short* __restrict__ dpB) {
  const int half = blockIdx.x & 1;
  const int ob = blockIdx.x >> 1;
  const bool is_dp = (ob >= EP_BLOCKS);
  const int row0 = (is_dp ? ob - EP_BLOCKS : ob) * 64;
  const int nrows = is_dp ? DP_ROWS : EP_ROWS;
  const float* __restrict__ src = is_dp ? dec : enc;
  const short* __restrict__ bb = WfB + (is_dp ? WF_PART : 0);  // packed
  short* __restrict__ out = is_dp ? dpB : epB;

  __shared__ short As[64 * 320];  // 40 KB, XOR-swizzled
  const int tid = threadIdx.x;

  #pragma unroll
  for (int it = 0; it < 10; ++it) {
    int chunk = it * 256 + tid;        // 2560 chunks of 8 elems
    int m = chunk / 40;
    int c = chunk - m * 40;
    int r = row0 + m;
    short8 hv;
    #pragma unroll
    for (int j = 0; j < 8; ++j) hv[j] = 0;
    if (r < nrows) {
      const float* p = src + (size_t)r * 320 + c * 8;
      float4 a0 = *(const float4*)p;
      float4 a1 = *(const float4*)(p + 4);
      hv[0] = f2bf(a0.x); hv[1] = f2bf(a0.y); hv[2] = f2bf(a0.z); hv[3] = f2bf(a0.w);
      hv[4] = f2bf(a1.x); hv[5] = f2bf(a1.y); hv[6] = f2bf(a1.z); hv[7] = f2bf(a1.w);
    }
    int off = (m * 640 + c * 16) ^ ((m & 7) << 4);
    *(short8*)((char*)As + off) = hv;
  }
  __syncthreads();

  const int lane = tid & 63, wid = tid >> 6;
  const int lr = lane & 15, g = lane >> 4;

  int lin[4], xm[4];
  #pragma unroll
  for (int mf = 0; mf < 4; ++mf) {
    int row = mf * 16 + lr;
    lin[mf] = row * 640 + g * 16;
    xm[mf] = (row & 7) << 4;
  }

  const int n0 = half * 256 + wid * 64;
  const short* bptr[4];
  float bfc[4];
  #pragma unroll
  for (int nf2 = 0; nf2 < 4; ++nf2) {
    bptr[nf2] = bb + (n0 / 16 + nf2) * 5120 + lane * 8;   // frag-linear
    bfc[nf2] = is_dp ? bfv[n0 + nf2 * 16 + lr] : 0.f;
  }
  f32x4 acc[4][4];
  #pragma unroll
  for (int mf = 0; mf < 4; ++mf)
    #pragma unroll
    for (int nf2 = 0; nf2 < 4; ++nf2)
      acc[mf][nf2] = (f32x4){0.f, 0.f, 0.f, 0.f};

  #pragma unroll 2
  for (int kk = 0; kk < 10; ++kk) {
    bf16x8 av[4], bv[4];
    #pragma unroll
    for (int mf = 0; mf < 4; ++mf) {
      int off = (lin[mf] + (kk << 6)) ^ xm[mf];
      av[mf] = __builtin_bit_cast(bf16x8, *(const short8*)((const char*)As + off));
    }
    #pragma unroll
    for (int nf2 = 0; nf2 < 4; ++nf2)
      bv[nf2] = __builtin_bit_cast(bf16x8, *(const short8*)(bptr[nf2] + kk * 512));
    #pragma unroll
    for (int mf = 0; mf < 4; ++mf)
      #pragma unroll
      for (int nf2 = 0; nf2 < 4; ++nf2)
        acc[mf][nf2] = __builtin_amdgcn_mfma_f32_16x16x32_bf16(av[mf], bv[nf2], acc[mf][nf2], 0, 0, 0);
  }
  #pragma unroll
  for (int mf = 0; mf < 4; ++mf)
    #pragma unroll
    for (int nf2 = 0; nf2 < 4; ++nf2)
      #pragma unroll
      for (int rr = 0; rr < 4; ++rr) {
        int rowl = mf * 16 + g * 4 + rr;
        int grow = row0 + rowl;
        if (grow < nrows) {
          int col = n0 + nf2 * 16 + lr;
          out[(size_t)grow * NINNER + col] = f2bf(acc[mf][nf2][rr] + bfc[nf2]);
        }
      }
}

// ---------------- Kernel 1.5: hpack — h = tanh(ep+dp) -> fp8 A-frag pack ----
// r19: de-fuse tanh from joint. Output layout = A-fragment-linear (validated
// by r18's passing fp8 joint): byte hpk[rg*8192 + kk*512 + l*8 + j] holds
// h[row = rg*16 + (l&15)][k = kk*32 + (l>>4)*8 + j]. ~50MB, L3-resident.
__global__ __launch_bounds__(256) void hpack_kernel(
    const short* __restrict__ epB, const short* __restrict__ dpB,
    char* __restrict__ hpk) {
  int gt = blockIdx.x * 256 + threadIdx.x;     // [0, NRG*1024)
  int rg = gt >> 10;
  int tl = gt & 1023;
  int kk = tl >> 6;
  int l = tl & 63;
  int row = rg * 16 + (l & 15);
  if (row >= NROWS) row = 0;                   // pad rows: harmless data
  int b = row / (T_DIM * UP1);
  int rem = row - b * (T_DIM * UP1);
  int t = rem / UP1;
  int u = rem - t * UP1;
  int k0 = kk * 32 + ((l >> 4) << 3);
  short8 ev = *(const short8*)(epB + (b * T_DIM + t) * NINNER + k0);
  short8 dv = *(const short8*)(dpB + (b * UP1 + u) * NINNER + k0);
  float h[8];
  #pragma unroll
  for (int j = 0; j < 8; ++j) h[j] = tanh_fast(bf2f(ev[j]) + bf2f(dv[j]));
  int2v w;
  w[0] = pkf8<true>(h[2], h[3], pkf8<false>(h[0], h[1], 0));
  w[1] = pkf8<true>(h[6], h[7], pkf8<false>(h[4], h[5], 0));
  *(int2v*)(hpk + (size_t)rg * 8192 + kk * 512 + l * 8) = w;
}

// ---------------- Kernel 2a: joint2 — barrier-free fp8 GEMM + softmax -------
// r19: no Phase-A, no staging barriers. Pure stream: A-frags from hpk (L3),
// B-frags from WpB8 (L2), 16x16x32_fp8_fp8 MFMA, base-2 fold. 8 waves
// free-run -> fold VALU of one wave overlaps MFMA of others (m114). One
// barrier before the epilogue. LOG2-domain outputs into padded Z (r12).
#define JROWS 64
__global__ __launch_bounds__(512) void joint2_kernel(
    const char* __restrict__ hpk, const char* __restrict__ WpB8,
    const float* __restrict__ bp, const int* __restrict__ tgt,
    float* __restrict__ Z) {
  __shared__ int bld_off[JROWS], eld_off[JROWS], tgt_s[JROWS];
  __shared__ float l0_s[JROWS], lt_s[JROWS];
  __shared__ float ws_s[8][JROWS];

  const int tid = threadIdx.x;
  const int row0 = blockIdx.x * JROWS;

  if (tid < JROWS) {
    int gr = row0 + tid;
    if (gr < NROWS) {
      int b = gr / (T_DIM * UP1);
      int rem = gr - b * (T_DIM * UP1);
      int t = rem / UP1;
      int u = rem - t * UP1;
      int zrow = (b * NDIAG + (t + u)) * ZSTR;
      bld_off[tid] = zrow + 4 + 2 * u;
      eld_off[tid] = (u < U_DIM) ? (zrow + 4 + 2 * u + 1) : -1;
      tgt_s[tid] = (u < U_DIM) ? tgt[b * U_DIM + u] : 0;
    } else {
      bld_off[tid] = -1; eld_off[tid] = -1; tgt_s[tid] = 0;
    }
    l0_s[tid] = 0.f; lt_s[tid] = 0.f;
  }
  __syncthreads();

  const int lane = tid & 63, wid = tid >> 6;
  const int lr = lane & 15, g = lane >> 4;

  const char* aptr[4];
  #pragma unroll
  for (int mf = 0; mf < 4; ++mf)
    aptr[mf] = hpk + (size_t)(row0 / 16 + mf) * 8192 + lane * 8;
  int tv[4][4];
  #pragma unroll
  for (int mf = 0; mf < 4; ++mf)
    #pragma unroll
    for (int rr = 0; rr < 4; ++rr)
      tv[mf][rr] = tgt_s[mf * 16 + g * 4 + rr];

  float rsum[4][4];
  #pragma unroll
  for (int mf = 0; mf < 4; ++mf)
    #pragma unroll
    for (int rr = 0; rr < 4; ++rr) rsum[mf][rr] = 0.f;

  #pragma unroll
  for (int sc = 0; sc < 2; ++sc) {
    const int n0 = wid * 128 + sc * 64;
    const char* bptr[4];
    float bpv[4];
    #pragma unroll
    for (int nf = 0; nf < 4; ++nf) {
      bptr[nf] = WpB8 + (n0 / 16 + nf) * 8192 + lane * 8;   // frag-linear fp8
      bpv[nf] = bp[n0 + nf * 16 + lr] * LOG2E;              // scaled bias
    }
    f32x4 acc[4][4];
    #pragma unroll
    for (int mf = 0; mf < 4; ++mf)
      #pragma unroll
      for (int nf = 0; nf < 4; ++nf)
        acc[mf][nf] = (f32x4){0.f, 0.f, 0.f, 0.f};

    #pragma unroll 4
    for (int kk = 0; kk < 16; ++kk) {
      long av[4], bv[4];
      #pragma unroll
      for (int mf = 0; mf < 4; ++mf)
        av[mf] = load8(aptr[mf] + kk * 512);
      #pragma unroll
      for (int nf = 0; nf < 4; ++nf)
        bv[nf] = load8(bptr[nf] + kk * 512);
      #pragma unroll
      for (int mf = 0; mf < 4; ++mf)
        #pragma unroll
        for (int nf = 0; nf < 4; ++nf)
          acc[mf][nf] = __builtin_amdgcn_mfma_f32_16x16x32_fp8_fp8(av[mf], bv[nf], acc[mf][nf], 0, 0, 0);
    }
    // fold: base-2 sum-of-exp2 over this 64-col subchunk (scaled logits)
    #pragma unroll
    for (int mf = 0; mf < 4; ++mf)
      #pragma unroll
      for (int rr = 0; rr < 4; ++rr) {
        float x0 = __builtin_fmaf(acc[mf][0][rr], LOG2E, bpv[0]);
        float x1 = __builtin_fmaf(acc[mf][1][rr], LOG2E, bpv[1]);
        float x2 = __builtin_fmaf(acc[mf][2][rr], LOG2E, bpv[2]);
        float x3 = __builtin_fmaf(acc[mf][3][rr], LOG2E, bpv[3]);
        int rowl = mf * 16 + g * 4 + rr;
        if (wid == 0 && sc == 0 && lr == 0) l0_s[rowl] = x0;  // v = 0 (scaled)
        int dtv = tv[mf][rr] - n0;
        if (dtv >= 0 && dtv < 64 && (dtv & 15) == lr) {
          int nfi = dtv >> 4;
          lt_s[rowl] = (nfi == 0) ? x0 : (nfi == 1) ? x1 : (nfi == 2) ? x2 : x3;
        }
        rsum[mf][rr] += __builtin_amdgcn_exp2f(x0) + __builtin_amdgcn_exp2f(x1)
                      + __builtin_amdgcn_exp2f(x2) + __builtin_amdgcn_exp2f(x3);
      }
  }
  // add-butterfly across the 16 lanes of each group
  #pragma unroll
  for (int mf = 0; mf < 4; ++mf)
    #pragma unroll
    for (int rr = 0; rr < 4; ++rr) {
      float s_ = rsum[mf][rr];
      #pragma unroll
      for (int o = 1; o < 16; o <<= 1) s_ += __shfl_xor(s_, o);
      if (lr == 0) ws_s[wid][mf * 16 + g * 4 + rr] = s_;
    }
  __syncthreads();
  if (tid < JROWS) {
    int bo = bld_off[tid];
    if (bo >= 0) {
      float S = 0.f;
      #pragma unroll
      for (int w = 0; w < 8; ++w) S += ws_s[w][tid];
      float lse2v = __builtin_amdgcn_logf(S);   // log2
      Z[bo] = l0_s[tid] - lse2v;                // LOG2 DOMAIN, blank slot
      int eo = eld_off[tid];
      if (eo >= 0) Z[eo] = lt_s[tid] - lse2v;   // emit slot
    }
  }
}

// ---------------- Kernel 2b: fused joint (r18 fallback if ws too small) -----
__global__ __launch_bounds__(512) void joint_fused_kernel(
    const short* __restrict__ epB, const short* __restrict__ dpB,
    const char* __restrict__ WpB8, const float* __restrict__ bp,
    const int* __restrict__ tgt, float* __restrict__ Z) {
  extern __shared__ char hbuf[];  // 64 * 512 = 32768 B (fp8 h)
  __shared__ int ep_off[JROWS], dp_off[JROWS], bld_off[JROWS], eld_off[JROWS], tgt_s[JROWS];
  __shared__ float l0_s[JROWS], lt_s[JROWS];
  __shared__ float ws_s[8][JROWS];

  const int tid = threadIdx.x;
  const int row0 = blockIdx.x * JROWS;

  if (tid < JROWS) {
    int gr = row0 + tid;
    if (gr < NROWS) {
      int b = gr / (T_DIM * UP1);
      int rem = gr - b * (T_DIM * UP1);
      int t = rem / UP1;
      int u = rem - t * UP1;
      ep_off[tid] = (b * T_DIM + t) * NINNER;
      dp_off[tid] = (b * UP1 + u) * NINNER;
      int zrow = (b * NDIAG + (t + u)) * ZSTR;
      bld_off[tid] = zrow + 4 + 2 * u;
      eld_off[tid] = (u < U_DIM) ? (zrow + 4 + 2 * u + 1) : -1;
      tgt_s[tid] = (u < U_DIM) ? tgt[b * U_DIM + u] : 0;
    } else {
      ep_off[tid] = 0; dp_off[tid] = 0; bld_off[tid] = -1; eld_off[tid] = -1; tgt_s[tid] = 0;
    }
    l0_s[tid] = 0.f; lt_s[tid] = 0.f;
  }
  __syncthreads();

  const int m0 = tid >> 4;
  const int m1 = 32 + m0;
  const int cq = tid & 15;
  const short* pe0 = epB + ep_off[m0] + cq * 8;
  const short* pd0 = dpB + dp_off[m0] + cq * 8;
  const short* pe1 = epB + ep_off[m1] + cq * 8;
  const short* pd1 = dpB + dp_off[m1] + cq * 8;
  const int po0 = ((m0 << 9) + (cq << 3)) ^ ((m0 & 7) << 3);
  const int po1 = ((m1 << 9) + (cq << 3)) ^ ((m1 & 7) << 3);

  short8 sev0, sdv0, sev1, sdv1;
#define STAGE_LOAD(q)                                  \
  {                                                    \
    sev0 = *(const short8*)(pe0 + (q) * 128);          \
    sdv0 = *(const short8*)(pd0 + (q) * 128);          \
    sev1 = *(const short8*)(pe1 + (q) * 128);          \
    sdv1 = *(const short8*)(pd1 + (q) * 128);          \
  }
#define STAGE_WRITE(q)                                                    \
  {                                                                       \
    float h0[8], h1[8];                                                   \
    _Pragma("unroll")                                                     \
    for (int j = 0; j < 8; ++j) {                                         \
      h0[j] = tanh_fast(bf2f(sev0[j]) + bf2f(sdv0[j]));                   \
      h1[j] = tanh_fast(bf2f(sev1[j]) + bf2f(sdv1[j]));                   \
    }                                                                     \
    int2v w0, w1;                                                         \
    w0[0] = pkf8<true>(h0[2], h0[3], pkf8<false>(h0[0], h0[1], 0));       \
    w0[1] = pkf8<true>(h0[6], h0[7], pkf8<false>(h0[4], h0[5], 0));       \
    w1[0] = pkf8<true>(h1[2], h1[3], pkf8<false>(h1[0], h1[1], 0));       \
    w1[1] = pkf8<true>(h1[6], h1[7], pkf8<false>(h1[4], h1[5], 0));       \
    *(int2v*)(hbuf + po0 + (q) * 128) = w0;                               \
    *(int2v*)(hbuf + po1 + (q) * 128) = w1;                               \
  }

  STAGE_LOAD(0)
  STAGE_WRITE(0)
  __syncthreads();   // quarter 0 resident

  const int lane = tid & 63, wid = tid >> 6;
  const int lr = lane & 15, g = lane >> 4;

  int lin[4];
  #pragma unroll
  for (int mf = 0; mf < 4; ++mf)
    lin[mf] = ((mf * 16 + lr) << 9) + (g << 3);
  const int xm = (lr & 7) << 3;   // (mf*16+lr)&7 == lr&7
  int tv[4][4];
  #pragma unroll
  for (int mf = 0; mf < 4; ++mf)
    #pragma unroll
    for (int rr = 0; rr < 4; ++rr)
      tv[mf][rr] = tgt_s[mf * 16 + g * 4 + rr];

  float rsum[4][4];
  #pragma unroll
  for (int mf = 0; mf < 4; ++mf)
    #pragma unroll
    for (int rr = 0; rr < 4; ++rr) rsum[mf][rr] = 0.f;

  #pragma unroll
  for (int sc = 0; sc < 2; ++sc) {
    const int n0 = wid * 128 + sc * 64;
    const char* bptr[4];
    float bpv[4];
    #pragma unroll
    for (int nf = 0; nf < 4; ++nf) {
      bptr[nf] = WpB8 + (n0 / 16 + nf) * 8192 + lane * 8;   // frag-linear fp8
      bpv[nf] = bp[n0 + nf * 16 + lr] * LOG2E;              // scaled bias
    }
    f32x4 acc[4][4];
    #pragma unroll
    for (int mf = 0; mf < 4; ++mf)
      #pragma unroll
      for (int nf = 0; nf < 4; ++nf)
        acc[mf][nf] = (f32x4){0.f, 0.f, 0.f, 0.f};

    #pragma unroll
    for (int qq = 0; qq < 4; ++qq) {
      if (sc == 0 && qq < 3) STAGE_LOAD(qq + 1)   // issue early
      #pragma unroll
      for (int i = 0; i < 4; ++i) {
        const int kk = qq * 4 + i;
        long av[4], bv[4];
        #pragma unroll
        for (int mf = 0; mf < 4; ++mf) {
          int off = ((lin[mf] + ((kk & 3) << 5)) ^ xm) + ((kk >> 2) << 7);
          av[mf] = load8(hbuf + off);
        }
        #pragma unroll
        for (int nf = 0; nf < 4; ++nf)
          bv[nf] = load8(bptr[nf] + kk * 512);
        #pragma unroll
        for (int mf = 0; mf < 4; ++mf)
          #pragma unroll
          for (int nf = 0; nf < 4; ++nf)
            acc[mf][nf] = __builtin_amdgcn_mfma_f32_16x16x32_fp8_fp8(av[mf], bv[nf], acc[mf][nf], 0, 0, 0);
      }
      if (sc == 0 && qq < 3) {
        STAGE_WRITE(qq + 1)                        // write late, then publish
        __syncthreads();
      }
    }
    #pragma unroll
    for (int mf = 0; mf < 4; ++mf)
      #pragma unroll
      for (int rr = 0; rr < 4; ++rr) {
        float x0 = __builtin_fmaf(acc[mf][0][rr], LOG2E, bpv[0]);
        float x1 = __builtin_fmaf(acc[mf][1][rr], LOG2E, bpv[1]);
        float x2 = __builtin_fmaf(acc[mf][2][rr], LOG2E, bpv[2]);
        float x3 = __builtin_fmaf(acc[mf][3][rr], LOG2E, bpv[3]);
        int rowl = mf * 16 + g * 4 + rr;
        if (wid == 0 && sc == 0 && lr == 0) l0_s[rowl] = x0;  // v = 0 (scaled)
        int dtv = tv[mf][rr] - n0;
        if (dtv >= 0 && dtv < 64 && (dtv & 15) == lr) {
          int nfi = dtv >> 4;
          lt_s[rowl] = (nfi == 0) ? x0 : (nfi == 1) ? x1 : (nfi == 2) ? x2 : x3;
        }
        rsum[mf][rr] += __builtin_amdgcn_exp2f(x0) + __builtin_amdgcn_exp2f(x1)
                      + __builtin_amdgcn_exp2f(x2) + __builtin_amdgcn_exp2f(x3);
      }
  }
  #pragma unroll
  for (int mf = 0; mf < 4; ++mf)
    #pragma unroll
    for (int rr = 0; rr < 4; ++rr) {
      float s_ = rsum[mf][rr];
      #pragma unroll
      for (int o = 1; o < 16; o <<= 1) s_ += __shfl_xor(s_, o);
      if (lr == 0) ws_s[wid][mf * 16 + g * 4 + rr] = s_;
    }
  __syncthreads();
  if (tid < JROWS) {
    int bo = bld_off[tid];
    if (bo >= 0) {
      float S = 0.f;
      #pragma unroll
      for (int w = 0; w < 8; ++w) S += ws_s[w][tid];
      float lse2v = __builtin_amdgcn_logf(S);   // log2
      Z[bo] = l0_s[tid] - lse2v;                // LOG2 DOMAIN, blank slot
      int eo = eld_off[tid];
      if (eo >= 0) Z[eo] = lt_s[tid] - lse2v;   // emit slot
    }
  }
}

// ---------------- Kernel 3: alpha DP — float4 operand quads (r12) -----------
#define ACH 8
#define NCH 48   /* s1 reaches 383 >= dstar max 379; slack rows cover tail */
__global__ __launch_bounds__(256) void alpha_kernel(
    const float* __restrict__ Z,
    const int* __restrict__ ilen, const int* __restrict__ ulen_,
    float* __restrict__ out) {
  __shared__ float lls[B_DIM];
  const int tid = threadIdx.x;
  const int b = tid >> 6;
  const int lane = tid & 63;
  const float NEG = NEGF;
  const int tl = ilen[b], ul = ulen_[b];
  const int dstar = tl - 1 + ul;          // final-cell diagonal

  const int u0 = lane;           // slot 0: u = 0..63
  const int u1 = 64 + lane;      // slot 1: u = 64..80 (lane < 17)
  const bool act1 = (u1 <= 80);
  const int uc1 = act1 ? u1 : 80;

  const float* Zb = Z + (size_t)b * (NDIAG * ZSTR);

  f32x4 Aq0[ACH], Aq1[ACH], Bq0[ACH], Bq1[ACH];

  #define ALOAD(P, c)                                                        \
    {                                                                        \
      const float* base0 = Zb + (c) * (ACH * ZSTR) + 1 + 2 * u0;             \
      const float* base1 = Zb + (c) * (ACH * ZSTR) + 1 + 2 * uc1;            \
      _Pragma("unroll")                                                      \
      for (int j = 0; j < ACH; ++j) {                                        \
        P##q0[j] = load4u(base0 + j * ZSTR);                                 \
        P##q1[j] = load4u(base1 + j * ZSTR);                                 \
      }                                                                      \
    }

  #define ACOMP(P, c)                                                        \
    {                                                                        \
      _Pragma("unroll")                                                      \
      for (int q = 0; q < ACH / 2; ++q) {                                    \
        const int j = 2 * q;                                                 \
        const int s1 = (c) * ACH + j + 1;                                    \
        float a63 = readlanef(pa0, 63), a62 = readlanef(pa0, 62);            \
        float s0m1 = ror1f(pa0);                                             \
        float s0m2 = ror1f(s0m1);                                            \
        float s1m1r = ror1f(pa1);                                            \
        float s1m2r = ror1f(s1m1r);                                          \
        float s1m1 = (lane == 0) ? a63 : s1m1r;                              \
        float s1m2 = (lane == 0) ? a62 : ((lane == 1) ? a63 : s1m2r);        \
        float na0, na1;                                                      \
        { /* slot 0 — v={e1m,b1m,e1,b1}, w=next row */                       \
          f32x4 v = P##q0[j], w = P##q0[j + 1];                              \
          float T1 = v[3] + w[3];                                            \
          float T2 = lse2_2(v[2] + w[3], v[1] + w[2]);                       \
          float T3 = v[0] + w[2];                                            \
          float p0 = pa0 + T1;                                               \
          float p1 = s0m1 + T2;                                              \
          float p2 = s0m2 + T3;                                              \
          float mx = fmaxf(fmaxf(p0, p1), p2);                               \
          float ss = __builtin_amdgcn_exp2f(p0 - mx)                         \
                   + __builtin_amdgcn_exp2f(p1 - mx)                         \
                   + __builtin_amdgcn_exp2f(p2 - mx);                        \
          na0 = fmaxf(mx + __builtin_amdgcn_logf(ss), NEG);                  \
        }                                                                    \
        { /* slot 1 */                                                       \
          f32x4 v = P##q1[j], w = P##q1[j + 1];                              \
          float T1 = v[3] + w[3];                                            \
          float T2 = lse2_2(v[2] + w[3], v[1] + w[2]);                       \
          float T3 = v[0] + w[2];                                            \
          float p0 = pa1 + T1;                                               \
          float p1 = s1m1 + T2;                                              \
          float p2 = s1m2 + T3;                                              \
          float mx = fmaxf(fmaxf(p0, p1), p2);                               \
          float ss = __builtin_amdgcn_exp2f(p0 - mx)                         \
                   + __builtin_amdgcn_exp2f(p1 - mx)                         \
                   + __builtin_amdgcn_exp2f(p2 - mx);                        \
          na1 = fmaxf(mx + __builtin_amdgcn_logf(ss), NEG);                  \
        }                                                                    \
        if (s1 == dstar) { /* odd-diagonal final capture */                  \
          float vo0 = lse2_2(pa0 + P##q0[j][3], s0m1 + P##q0[j][2]);         \
          if (u0 == ul) fin = vo0;                                           \
          float vo1 = lse2_2(pa1 + P##q1[j][3], s1m1 + P##q1[j][2]);         \
          if (act1 && u1 == ul) fin = vo1;                                   \
        }                                                                    \
        pa0 = na0; pa1 = na1;                                                \
        if (s1 + 1 == dstar) { /* even-diagonal final capture */             \
          if (u0 == ul) fin = pa0;                                           \
          if (act1 && u1 == ul) fin = pa1;                                   \
        }                                                                    \
      }                                                                      \
    }

  float pa0 = (u0 == 0) ? 0.f : NEG;  // alpha on diag 0 (log2 domain)
  float pa1 = NEG;
  float fin = NEG;
  if (dstar == 0 && u0 == ul) fin = pa0;   // tl=1, ul=0 corner

  ALOAD(A, 0);
  for (int p = 0; p < NCH / 2; ++p) {
    const int cA = 2 * p, cB = 2 * p + 1;
    ALOAD(B, cB);        // issue next chunk's loads (covered by ACOMP(A))
    ACOMP(A, cA);
    ALOAD(A, cA + 2);    // tail chunks read NEG slack rows — harmless
    ACOMP(B, cB);
  }

  #pragma unroll
  for (int o = 32; o; o >>= 1) fin = fmaxf(fin, __shfl_xor(fin, o));
  if (lane == 0) {
    float last = Zb[(size_t)dstar * ZSTR + 4 + 2 * ul];   // blank, log2 domain
    lls[b] = fin + last;
  }
  __syncthreads();
  if (tid == 0)
    out[0] = -(lls[0] + lls[1] + lls[2] + lls[3]) * (LN2 * 0.25f);
}

// ---------------- launcher ----------------
extern "C" void kernel_launch(void* const* d_in, const int* in_sizes, int n_in,
                              void* d_out, int out_size, void* d_ws, size_t ws_size,
                              hipStream_t stream) {
  const float* enc = (const float*)d_in[0];
  const float* dec = (const float*)d_in[1];
  const float* Wf  = (const float*)d_in[2];
  const float* bfv = (const float*)d_in[3];
  const float* Wp  = (const float*)d_in[4];
  const float* bp  = (const float*)d_in[5];
  const int* targets = (const int*)d_in[6];
  const int* ilen    = (const int*)d_in[7];
  const int* ulen    = (const int*)d_in[8];
  float* out = (float*)d_out;
  char* ws = (char*)d_ws;

  short* WfB  = (short*)(ws + 0);          //   655360 B (bf16 packed)
  char*  WpB8 = (char*)(ws + 655360);      //   524288 B (fp8 packed) -> 1179648
  short* epB  = (short*)(ws + 1179648);    //  1228800 B (bf16)       -> 2408448
  short* dpB  = (short*)(ws + 2408448);    //   331776 B (bf16)       -> 2740224
  float* Z    = (float*)(ws + 2740224);    //  1026816 B              -> 3767040
  char*  hpk  = (char*)(ws + 3767040);     // 49807360 B (fp8 A-frag) -> 53574400

  const size_t WS_NEED_SPLIT = 53574400;

  cvt_kernel<<<1083, 256, 0, stream>>>(Wf, Wp, WfB, WpB8, Z);
  proj_kernel<<<50, 256, 0, stream>>>(enc, dec, WfB, bfv, epB, dpB);
  if (ws_size >= WS_NEED_SPLIT) {
    hpack_kernel<<<NRG * 4, 256, 0, stream>>>(epB, dpB, hpk);
    joint2_kernel<<<(NROWS + JROWS - 1) / JROWS, 512, 0, stream>>>(hpk, WpB8, bp, targets, Z);
  } else {
    joint_fused_kernel<<<(NROWS + JROWS - 1) / JROWS, 512, 32768, stream>>>(epB, dpB, WpB8, bp, targets, Z);
  }
  alpha_kernel<<<1, 256, 0, stream>>>(Z, ilen, ulen, out);
}

// Round 20
// 186.552 us; speedup vs baseline: 1.2334x; 1.2334x over previous
//
#include <hip/hip_runtime.h>

#define B_DIM 4
#define T_DIM 300
#define U_DIM 80
#define UP1   81
#define V_DIM 1024
#define NINNER 512
#define NROWS (B_DIM * T_DIM * UP1)   /* 97200 */
#define EP_ROWS (B_DIM * T_DIM)       /* 1200 */
#define DP_ROWS (B_DIM * UP1)         /* 324 */
#define NDIAG 380                      /* t+u diagonals */
#define ZSTR  168                      /* Z row stride in floats: 4 pad + 162, 16B-aligned */
#define ZROWS (B_DIM * NDIAG + 8)      /* + 8 NEG slack rows (no-clamp ALOAD) */
#define WF_PART 163840                 /* 512 cols x 320 k, per half of Wf */
#define LOG2E 1.44269504088896341f
#define LN2   0.69314718055994531f
#define NEGF  -1e30f

typedef float f32x4 __attribute__((ext_vector_type(4)));
typedef short short8 __attribute__((ext_vector_type(8)));
typedef short short4v __attribute__((ext_vector_type(4)));
typedef __bf16 bf16x8 __attribute__((ext_vector_type(8)));
typedef int int2v __attribute__((ext_vector_type(2)));

static __device__ __forceinline__ short f2bf(float f) {
  return (short)__builtin_bit_cast(unsigned short, (__bf16)f);  // native cvt (RNE)
}
static __device__ __forceinline__ float bf2f(short s) {
  unsigned int u = ((unsigned int)(unsigned short)s) << 16;
  return __builtin_bit_cast(float, u);
}
static __device__ __forceinline__ float tanh_fast(float x) {
  float e = __builtin_amdgcn_exp2f(x * 2.88539008177792681f); // exp(2x)
  return 1.0f - 2.0f * __builtin_amdgcn_rcpf(e + 1.0f);
}
// base-2 logsumexp of 2 terms (finite-NEG safe)
static __device__ __forceinline__ float lse2_2(float a, float b) {
  float mx = fmaxf(a, b), mn = fminf(a, b);
  return mx + __builtin_amdgcn_logf(1.0f + __builtin_amdgcn_exp2f(mn - mx));
}
// DPP wave_ror:1 — dst[i] = src[(i+63)&63]; VALU pipe, no LDS unit (r11).
static __device__ __forceinline__ float ror1f(float x) {
  int r = __builtin_amdgcn_update_dpp(0, __builtin_bit_cast(int, x),
                                      0x13C /*WAVE_ROR1*/, 0xF, 0xF, true);
  return __builtin_bit_cast(float, r);
}
static __device__ __forceinline__ float readlanef(float x, int l) {
  return __builtin_bit_cast(float,
      __builtin_amdgcn_readlane(__builtin_bit_cast(int, x), l));
}
// 16B load at 4B alignment (Z operand quads sit at odd float indices)
static __device__ __forceinline__ f32x4 load4u(const float* p) {
  f32x4 v;
  __builtin_memcpy(&v, p, 16);
  return v;
}
static __device__ __forceinline__ long load8(const void* p) {
  long v;
  __builtin_memcpy(&v, p, 8);
  return v;
}
// HW fp8 e4m3 pack: 2 f32 -> 2 fp8 bytes; HI must be an immediate (r17 fix).
template <bool HI>
static __device__ __forceinline__ int pkf8(float a, float b, int old) {
  return __builtin_amdgcn_cvt_pk_fp8_f32(a, b, old, HI);
}

// ---------------- Kernel 0: weight cvt/pack + Z NEG-prefill -----------------
// Wf -> bf16 frag-linear (proj). Wp -> FP8 e4m3 frag-linear (r17):
// byte = ((c>>4)*16+(k>>5))*512 + (((k>>3)&3)*16+(c&15))*8 + (k&7).
#define CVT_NF 81920
#define CVT_NP 131072
#define FILL_N4 ((ZROWS * ZSTR) / 4)   /* 64176 */
__global__ __launch_bounds__(256) void cvt_kernel(
    const float* __restrict__ Wf, const float* __restrict__ Wp,
    short* __restrict__ WfB, char* __restrict__ WpB8, float* __restrict__ Z) {
  int idx = blockIdx.x * 256 + threadIdx.x;
  if (idx < CVT_NF) {
    float4 v = ((const float4*)Wf)[idx];
    int flat = idx * 4;
    int c = flat / 640;
    int kc = flat - c * 640;
    int part = (kc >= 320);
    int k0 = kc - (part ? 320 : 0);
    int dest = (part ? WF_PART : 0)
             + ((c >> 4) * 10 + (k0 >> 5)) * 512
             + (((k0 >> 3) & 3) * 16 + (c & 15)) * 8 + (k0 & 7);
    short4v o;
    o[0] = f2bf(v.x); o[1] = f2bf(v.y); o[2] = f2bf(v.z); o[3] = f2bf(v.w);
    *(short4v*)(WfB + dest) = o;
  } else if (idx < CVT_NF + CVT_NP) {
    int j = idx - CVT_NF;
    float4 v = ((const float4*)Wp)[j];
    int flat = j * 4;
    int c = flat >> 9;
    int k0 = flat & 511;
    int dest = ((c >> 4) * 16 + (k0 >> 5)) * 512
             + (((k0 >> 3) & 3) * 16 + (c & 15)) * 8 + (k0 & 7);
    int w = pkf8<false>(v.x, v.y, 0);
    w = pkf8<true>(v.z, v.w, w);
    *(int*)(WpB8 + dest) = w;     // dest is 4-aligned (k0&7 in {0,4})
  } else {
    int i = idx - (CVT_NF + CVT_NP);
    if (i < FILL_N4) ((f32x4*)Z)[i] = (f32x4){NEGF, NEGF, NEGF, NEGF};
  }
}

// ---------------- Kernel 1: enc/dec projections (MFMA bf16) ----------------
// NOTE: no min-waves arg — min-waves>=4 on MFMA kernels splits the unified
// RF (Arch 64 / AGPR 64) and spills (r2/r3).
#define EP_BLOCKS 19
__global__ __launch_bounds__(256) void proj_kernel(
    const float* __restrict__ enc, const float* __restrict__ dec,
    const short* __restrict__ WfB, const float* __restrict__ bfv,
    short* __restrict__ epB, short* __restrict__ dpB) {
  const int half = blockIdx.x & 1;
  const int ob = blockIdx.x >> 1;
  const bool is_dp = (ob >= EP_BLOCKS);
  const int row0 = (is_dp ? ob - EP_BLOCKS : ob) * 64;
  const int nrows = is_dp ? DP_ROWS : EP_ROWS;
  const float* __restrict__ src = is_dp ? dec : enc;
  const short* __restrict__ bb = WfB + (is_dp ? WF_PART : 0);  // packed
  short* __restrict__ out = is_dp ? dpB : epB;

  __shared__ short As[64 * 320];  // 40 KB, XOR-swizzled
  const int tid = threadIdx.x;

  #pragma unroll
  for (int it = 0; it < 10; ++it) {
    int chunk = it * 256 + tid;        // 2560 chunks of 8 elems
    int m = chunk / 40;
    int c = chunk - m * 40;
    int r = row0 + m;
    short8 hv;
    #pragma unroll
    for (int j = 0; j < 8; ++j) hv[j] = 0;
    if (r < nrows) {
      const float* p = src + (size_t)r * 320 + c * 8;
      float4 a0 = *(const float4*)p;
      float4 a1 = *(const float4*)(p + 4);
      hv[0] = f2bf(a0.x); hv[1] = f2bf(a0.y); hv[2] = f2bf(a0.z); hv[3] = f2bf(a0.w);
      hv[4] = f2bf(a1.x); hv[5] = f2bf(a1.y); hv[6] = f2bf(a1.z); hv[7] = f2bf(a1.w);
    }
    int off = (m * 640 + c * 16) ^ ((m & 7) << 4);
    *(short8*)((char*)As + off) = hv;
  }
  __syncthreads();

  const int lane = tid & 63, wid = tid >> 6;
  const int lr = lane & 15, g = lane >> 4;

  int lin[4], xm[4];
  #pragma unroll
  for (int mf = 0; mf < 4; ++mf) {
    int row = mf * 16 + lr;
    lin[mf] = row * 640 + g * 16;
    xm[mf] = (row & 7) << 4;
  }

  const int n0 = half * 256 + wid * 64;
  const short* bptr[4];
  float bfc[4];
  #pragma unroll
  for (int nf2 = 0; nf2 < 4; ++nf2) {
    bptr[nf2] = bb + (n0 / 16 + nf2) * 5120 + lane * 8;   // frag-linear
    bfc[nf2] = is_dp ? bfv[n0 + nf2 * 16 + lr] : 0.f;
  }
  f32x4 acc[4][4];
  #pragma unroll
  for (int mf = 0; mf < 4; ++mf)
    #pragma unroll
    for (int nf2 = 0; nf2 < 4; ++nf2)
      acc[mf][nf2] = (f32x4){0.f, 0.f, 0.f, 0.f};

  #pragma unroll 2
  for (int kk = 0; kk < 10; ++kk) {
    bf16x8 av[4], bv[4];
    #pragma unroll
    for (int mf = 0; mf < 4; ++mf) {
      int off = (lin[mf] + (kk << 6)) ^ xm[mf];
      av[mf] = __builtin_bit_cast(bf16x8, *(const short8*)((const char*)As + off));
    }
    #pragma unroll
    for (int nf2 = 0; nf2 < 4; ++nf2)
      bv[nf2] = __builtin_bit_cast(bf16x8, *(const short8*)(bptr[nf2] + kk * 512));
    #pragma unroll
    for (int mf = 0; mf < 4; ++mf)
      #pragma unroll
      for (int nf2 = 0; nf2 < 4; ++nf2)
        acc[mf][nf2] = __builtin_amdgcn_mfma_f32_16x16x32_bf16(av[mf], bv[nf2], acc[mf][nf2], 0, 0, 0);
  }
  #pragma unroll
  for (int mf = 0; mf < 4; ++mf)
    #pragma unroll
    for (int nf2 = 0; nf2 < 4; ++nf2)
      #pragma unroll
      for (int rr = 0; rr < 4; ++rr) {
        int rowl = mf * 16 + g * 4 + rr;
        int grow = row0 + rowl;
        if (grow < nrows) {
          int col = n0 + nf2 * 16 + lr;
          out[(size_t)grow * NINNER + col] = f2bf(acc[mf][nf2][rr] + bfc[nf2]);
        }
      }
}

// ---------------- Kernel 2: fused joint + log-softmax slices ----------------
// r18 CHAMPION (restored r20): JROWS 64, mf=4, 8 waves, K-quarter stage
// pipeline, GEMM in FP8 e4m3: h staged as fp8 (LDS 32KB, rows 512B), Wp fp8
// frag-linear (512KB), MFMA 16x16x32_fp8_fp8. Base-2 softmax; LOG2-domain
// outputs into interleaved padded Z (r12). 130.5us measured, absmax 0.0.
#define JROWS 64
__global__ __launch_bounds__(512) void joint_kernel(
    const short* __restrict__ epB, const short* __restrict__ dpB,
    const char* __restrict__ WpB8, const float* __restrict__ bp,
    const int* __restrict__ tgt, float* __restrict__ Z) {
  extern __shared__ char hbuf[];  // 64 * 512 = 32768 B (fp8 h)
  __shared__ int ep_off[JROWS], dp_off[JROWS], bld_off[JROWS], eld_off[JROWS], tgt_s[JROWS];
  __shared__ float l0_s[JROWS], lt_s[JROWS];
  __shared__ float ws_s[8][JROWS];

  const int tid = threadIdx.x;
  const int row0 = blockIdx.x * JROWS;

  if (tid < JROWS) {
    int gr = row0 + tid;
    if (gr < NROWS) {
      int b = gr / (T_DIM * UP1);
      int rem = gr - b * (T_DIM * UP1);
      int t = rem / UP1;
      int u = rem - t * UP1;
      ep_off[tid] = (b * T_DIM + t) * NINNER;
      dp_off[tid] = (b * UP1 + u) * NINNER;
      int zrow = (b * NDIAG + (t + u)) * ZSTR;
      bld_off[tid] = zrow + 4 + 2 * u;
      eld_off[tid] = (u < U_DIM) ? (zrow + 4 + 2 * u + 1) : -1;
      tgt_s[tid] = (u < U_DIM) ? tgt[b * U_DIM + u] : 0;
    } else {
      ep_off[tid] = 0; dp_off[tid] = 0; bld_off[tid] = -1; eld_off[tid] = -1; tgt_s[tid] = 0;
    }
    l0_s[tid] = 0.f; lt_s[tid] = 0.f;
  }
  __syncthreads();

  // stage-geometry: thread covers rows m0 and m0+32 at col-unit cq (8 elems);
  // quarter q shifts global cols by q*128 elems and LDS bytes by q*128.
  const int m0 = tid >> 4;
  const int m1 = 32 + m0;
  const int cq = tid & 15;
  const short* pe0 = epB + ep_off[m0] + cq * 8;
  const short* pd0 = dpB + dp_off[m0] + cq * 8;
  const short* pe1 = epB + ep_off[m1] + cq * 8;
  const short* pd1 = dpB + dp_off[m1] + cq * 8;
  const int po0 = ((m0 << 9) + (cq << 3)) ^ ((m0 & 7) << 3);
  const int po1 = ((m1 << 9) + (cq << 3)) ^ ((m1 & 7) << 3);

  short8 sev0, sdv0, sev1, sdv1;
#define STAGE_LOAD(q)                                  \
  {                                                    \
    sev0 = *(const short8*)(pe0 + (q) * 128);          \
    sdv0 = *(const short8*)(pd0 + (q) * 128);          \
    sev1 = *(const short8*)(pe1 + (q) * 128);          \
    sdv1 = *(const short8*)(pd1 + (q) * 128);          \
  }
#define STAGE_WRITE(q)                                                    \
  {                                                                       \
    float h0[8], h1[8];                                                   \
    _Pragma("unroll")                                                     \
    for (int j = 0; j < 8; ++j) {                                         \
      h0[j] = tanh_fast(bf2f(sev0[j]) + bf2f(sdv0[j]));                   \
      h1[j] = tanh_fast(bf2f(sev1[j]) + bf2f(sdv1[j]));                   \
    }                                                                     \
    int2v w0, w1;                                                         \
    w0[0] = pkf8<true>(h0[2], h0[3], pkf8<false>(h0[0], h0[1], 0));       \
    w0[1] = pkf8<true>(h0[6], h0[7], pkf8<false>(h0[4], h0[5], 0));       \
    w1[0] = pkf8<true>(h1[2], h1[3], pkf8<false>(h1[0], h1[1], 0));       \
    w1[1] = pkf8<true>(h1[6], h1[7], pkf8<false>(h1[4], h1[5], 0));       \
    *(int2v*)(hbuf + po0 + (q) * 128) = w0;                               \
    *(int2v*)(hbuf + po1 + (q) * 128) = w1;                               \
  }

  STAGE_LOAD(0)
  STAGE_WRITE(0)
  __syncthreads();   // quarter 0 resident

  const int lane = tid & 63, wid = tid >> 6;
  const int lr = lane & 15, g = lane >> 4;

  int lin[4];
  #pragma unroll
  for (int mf = 0; mf < 4; ++mf)
    lin[mf] = ((mf * 16 + lr) << 9) + (g << 3);
  const int xm = (lr & 7) << 3;   // (mf*16+lr)&7 == lr&7
  int tv[4][4];
  #pragma unroll
  for (int mf = 0; mf < 4; ++mf)
    #pragma unroll
    for (int rr = 0; rr < 4; ++rr)
      tv[mf][rr] = tgt_s[mf * 16 + g * 4 + rr];

  float rsum[4][4];
  #pragma unroll
  for (int mf = 0; mf < 4; ++mf)
    #pragma unroll
    for (int rr = 0; rr < 4; ++rr) rsum[mf][rr] = 0.f;

  #pragma unroll
  for (int sc = 0; sc < 2; ++sc) {
    const int n0 = wid * 128 + sc * 64;
    const char* bptr[4];
    float bpv[4];
    #pragma unroll
    for (int nf = 0; nf < 4; ++nf) {
      bptr[nf] = WpB8 + (n0 / 16 + nf) * 8192 + lane * 8;   // frag-linear fp8
      bpv[nf] = bp[n0 + nf * 16 + lr] * LOG2E;              // scaled bias
    }
    f32x4 acc[4][4];
    #pragma unroll
    for (int mf = 0; mf < 4; ++mf)
      #pragma unroll
      for (int nf = 0; nf < 4; ++nf)
        acc[mf][nf] = (f32x4){0.f, 0.f, 0.f, 0.f};

    #pragma unroll
    for (int qq = 0; qq < 4; ++qq) {
      if (sc == 0 && qq < 3) STAGE_LOAD(qq + 1)   // issue early
      #pragma unroll
      for (int i = 0; i < 4; ++i) {
        const int kk = qq * 4 + i;
        long av[4], bv[4];
        #pragma unroll
        for (int mf = 0; mf < 4; ++mf) {
          int off = ((lin[mf] + ((kk & 3) << 5)) ^ xm) + ((kk >> 2) << 7);
          av[mf] = load8(hbuf + off);
        }
        #pragma unroll
        for (int nf = 0; nf < 4; ++nf)
          bv[nf] = load8(bptr[nf] + kk * 512);
        #pragma unroll
        for (int mf = 0; mf < 4; ++mf)
          #pragma unroll
          for (int nf = 0; nf < 4; ++nf)
            acc[mf][nf] = __builtin_amdgcn_mfma_f32_16x16x32_fp8_fp8(av[mf], bv[nf], acc[mf][nf], 0, 0, 0);
      }
      if (sc == 0 && qq < 3) {
        STAGE_WRITE(qq + 1)                        // write late, then publish
        __syncthreads();
      }
    }
    // fold: base-2 sum-of-exp2 over this 64-col subchunk (scaled logits)
    #pragma unroll
    for (int mf = 0; mf < 4; ++mf)
      #pragma unroll
      for (int rr = 0; rr < 4; ++rr) {
        float x0 = __builtin_fmaf(acc[mf][0][rr], LOG2E, bpv[0]);
        float x1 = __builtin_fmaf(acc[mf][1][rr], LOG2E, bpv[1]);
        float x2 = __builtin_fmaf(acc[mf][2][rr], LOG2E, bpv[2]);
        float x3 = __builtin_fmaf(acc[mf][3][rr], LOG2E, bpv[3]);
        int rowl = mf * 16 + g * 4 + rr;
        if (wid == 0 && sc == 0 && lr == 0) l0_s[rowl] = x0;  // v = 0 (scaled)
        int dtv = tv[mf][rr] - n0;
        if (dtv >= 0 && dtv < 64 && (dtv & 15) == lr) {
          int nfi = dtv >> 4;
          lt_s[rowl] = (nfi == 0) ? x0 : (nfi == 1) ? x1 : (nfi == 2) ? x2 : x3;
        }
        rsum[mf][rr] += __builtin_amdgcn_exp2f(x0) + __builtin_amdgcn_exp2f(x1)
                      + __builtin_amdgcn_exp2f(x2) + __builtin_amdgcn_exp2f(x3);
      }
  }
  // add-butterfly across the 16 lanes of each group
  #pragma unroll
  for (int mf = 0; mf < 4; ++mf)
    #pragma unroll
    for (int rr = 0; rr < 4; ++rr) {
      float s_ = rsum[mf][rr];
      #pragma unroll
      for (int o = 1; o < 16; o <<= 1) s_ += __shfl_xor(s_, o);
      if (lr == 0) ws_s[wid][mf * 16 + g * 4 + rr] = s_;
    }
  __syncthreads();
  if (tid < JROWS) {
    int bo = bld_off[tid];
    if (bo >= 0) {
      float S = 0.f;
      #pragma unroll
      for (int w = 0; w < 8; ++w) S += ws_s[w][tid];
      float lse2v = __builtin_amdgcn_logf(S);   // log2
      Z[bo] = l0_s[tid] - lse2v;                // LOG2 DOMAIN, blank slot
      int eo = eld_off[tid];
      if (eo >= 0) Z[eo] = lt_s[tid] - lse2v;   // emit slot
    }
  }
}

// ---------------- Kernel 3: alpha DP — float4 operand quads (r12) -----------
#define ACH 8
#define NCH 48   /* s1 reaches 383 >= dstar max 379; slack rows cover tail */
__global__ __launch_bounds__(256) void alpha_kernel(
    const float* __restrict__ Z,
    const int* __restrict__ ilen, const int* __restrict__ ulen_,
    float* __restrict__ out) {
  __shared__ float lls[B_DIM];
  const int tid = threadIdx.x;
  const int b = tid >> 6;
  const int lane = tid & 63;
  const float NEG = NEGF;
  const int tl = ilen[b], ul = ulen_[b];
  const int dstar = tl - 1 + ul;          // final-cell diagonal

  const int u0 = lane;           // slot 0: u = 0..63
  const int u1 = 64 + lane;      // slot 1: u = 64..80 (lane < 17)
  const bool act1 = (u1 <= 80);
  const int uc1 = act1 ? u1 : 80;

  const float* Zb = Z + (size_t)b * (NDIAG * ZSTR);

  f32x4 Aq0[ACH], Aq1[ACH], Bq0[ACH], Bq1[ACH];

  #define ALOAD(P, c)                                                        \
    {                                                                        \
      const float* base0 = Zb + (c) * (ACH * ZSTR) + 1 + 2 * u0;             \
      const float* base1 = Zb + (c) * (ACH * ZSTR) + 1 + 2 * uc1;            \
      _Pragma("unroll")                                                      \
      for (int j = 0; j < ACH; ++j) {                                        \
        P##q0[j] = load4u(base0 + j * ZSTR);                                 \
        P##q1[j] = load4u(base1 + j * ZSTR);                                 \
      }                                                                      \
    }

  #define ACOMP(P, c)                                                        \
    {                                                                        \
      _Pragma("unroll")                                                      \
      for (int q = 0; q < ACH / 2; ++q) {                                    \
        const int j = 2 * q;                                                 \
        const int s1 = (c) * ACH + j + 1;                                    \
        /* neighbor alphas via DPP (VALU pipe) */                            \
        float a63 = readlanef(pa0, 63), a62 = readlanef(pa0, 62);            \
        float s0m1 = ror1f(pa0);                                             \
        float s0m2 = ror1f(s0m1);                                            \
        float s1m1r = ror1f(pa1);                                            \
        float s1m2r = ror1f(s1m1r);                                          \
        float s1m1 = (lane == 0) ? a63 : s1m1r;                              \
        float s1m2 = (lane == 0) ? a62 : ((lane == 1) ? a63 : s1m2r);        \
        float na0, na1;                                                      \
        { /* slot 0 — v={e1m,b1m,e1,b1}, w=next row */                       \
          f32x4 v = P##q0[j], w = P##q0[j + 1];                              \
          float T1 = v[3] + w[3];                                            \
          float T2 = lse2_2(v[2] + w[3], v[1] + w[2]);                       \
          float T3 = v[0] + w[2];                                            \
          float p0 = pa0 + T1;                                               \
          float p1 = s0m1 + T2;                                              \
          float p2 = s0m2 + T3;                                              \
          float mx = fmaxf(fmaxf(p0, p1), p2);                               \
          float ss = __builtin_amdgcn_exp2f(p0 - mx)                         \
                   + __builtin_amdgcn_exp2f(p1 - mx)                         \
                   + __builtin_amdgcn_exp2f(p2 - mx);                        \
          na0 = fmaxf(mx + __builtin_amdgcn_logf(ss), NEG);                  \
        }                                                                    \
        { /* slot 1 */                                                       \
          f32x4 v = P##q1[j], w = P##q1[j + 1];                              \
          float T1 = v[3] + w[3];                                            \
          float T2 = lse2_2(v[2] + w[3], v[1] + w[2]);                       \
          float T3 = v[0] + w[2];                                            \
          float p0 = pa1 + T1;                                               \
          float p1 = s1m1 + T2;                                              \
          float p2 = s1m2 + T3;                                              \
          float mx = fmaxf(fmaxf(p0, p1), p2);                               \
          float ss = __builtin_amdgcn_exp2f(p0 - mx)                         \
                   + __builtin_amdgcn_exp2f(p1 - mx)                         \
                   + __builtin_amdgcn_exp2f(p2 - mx);                        \
          na1 = fmaxf(mx + __builtin_amdgcn_logf(ss), NEG);                  \
        }                                                                    \
        if (s1 == dstar) { /* odd-diagonal final capture */                  \
          float vo0 = lse2_2(pa0 + P##q0[j][3], s0m1 + P##q0[j][2]);         \
          if (u0 == ul) fin = vo0;                                           \
          float vo1 = lse2_2(pa1 + P##q1[j][3], s1m1 + P##q1[j][2]);         \
          if (act1 && u1 == ul) fin = vo1;                                   \
        }                                                                    \
        pa0 = na0; pa1 = na1;                                                \
        if (s1 + 1 == dstar) { /* even-diagonal final capture */             \
          if (u0 == ul) fin = pa0;                                           \
          if (act1 && u1 == ul) fin = pa1;                                   \
        }                                                                    \
      }                                                                      \
    }

  float pa0 = (u0 == 0) ? 0.f : NEG;  // alpha on diag 0 (log2 domain)
  float pa1 = NEG;
  float fin = NEG;
  if (dstar == 0 && u0 == ul) fin = pa0;   // tl=1, ul=0 corner

  ALOAD(A, 0);
  for (int p = 0; p < NCH / 2; ++p) {
    const int cA = 2 * p, cB = 2 * p + 1;
    ALOAD(B, cB);        // issue next chunk's loads (covered by ACOMP(A))
    ACOMP(A, cA);
    ALOAD(A, cA + 2);    // tail chunks read NEG slack rows — harmless
    ACOMP(B, cB);
  }

  #pragma unroll
  for (int o = 32; o; o >>= 1) fin = fmaxf(fin, __shfl_xor(fin, o));
  if (lane == 0) {
    float last = Zb[(size_t)dstar * ZSTR + 4 + 2 * ul];   // blank, log2 domain
    lls[b] = fin + last;
  }
  __syncthreads();
  if (tid == 0)
    out[0] = -(lls[0] + lls[1] + lls[2] + lls[3]) * (LN2 * 0.25f);
}

// ---------------- launcher ----------------
extern "C" void kernel_launch(void* const* d_in, const int* in_sizes, int n_in,
                              void* d_out, int out_size, void* d_ws, size_t ws_size,
                              hipStream_t stream) {
  const float* enc = (const float*)d_in[0];
  const float* dec = (const float*)d_in[1];
  const float* Wf  = (const float*)d_in[2];
  const float* bfv = (const float*)d_in[3];
  const float* Wp  = (const float*)d_in[4];
  const float* bp  = (const float*)d_in[5];
  const int* targets = (const int*)d_in[6];
  const int* ilen    = (const int*)d_in[7];
  const int* ulen    = (const int*)d_in[8];
  float* out = (float*)d_out;
  char* ws = (char*)d_ws;

  short* WfB  = (short*)(ws + 0);          //   655360 B (bf16 packed)
  char*  WpB8 = (char*)(ws + 655360);      //   524288 B (fp8 packed) -> 1179648
  short* epB  = (short*)(ws + 1179648);    //  1228800 B (bf16)       -> 2408448
  short* dpB  = (short*)(ws + 2408448);    //   331776 B (bf16)       -> 2740224
  float* Z    = (float*)(ws + 2740224);    //  1026816 B              -> 3767040

  // cvt+pack (832 blocks) fused with Z NEG-prefill (251 tail blocks)
  cvt_kernel<<<1083, 256, 0, stream>>>(Wf, Wp, WfB, WpB8, Z);
  proj_kernel<<<50, 256, 0, stream>>>(enc, dec, WfB, bfv, epB, dpB);
  joint_kernel<<<(NROWS + JROWS - 1) / JROWS, 512, 32768, stream>>>(epB, dpB, WpB8, bp, targets, Z);
  alpha_kernel<<<1, 256, 0, stream>>>(Z, ilen, ulen, out);
}